// Round 4
// baseline (872.320 us; speedup 1.0000x reference)
//
#include <hip/hip_runtime.h>
#include <hip/hip_cooperative_groups.h>

namespace cg = cooperative_groups;

// Affinity propagation, [X=256,Y=256,Z=32] fp32, 9 steps fused in ONE
// cooperative kernel (256 blocks = 1/CU, guaranteed co-resident) with
// grid.sync() between steps. Fallback: 9 separate dispatches if the
// cooperative launch is rejected.
//
// Per step (dir = step%3), per voxel v:
//   g_k  = guidance[dir*8+k][v+off_k]  (0 if off-grid in the stencil plane)
//   out[v] = r[v] + (sum_k g_k*(r[v+off_k]-r[v])) / (sum_k |g_k|)
// k -> (d1,d2): (1,1),(1,0),(1,-1),(0,1),(0,-1),(-1,1),(-1,0),(-1,-1)
//   dir0: (d1,d2)->(x,y)  dir1: (x,z)  dir2: (y,z)
//
// All loads unconditional at clamped in-allocation addresses; guidance is
// zero-masked for off-grid neighbors (g=0 kills the whole term == zero-pad).

constexpr int X = 256, Y = 256, Z = 32;
constexpr int NV = X * Y * Z;        // 2097152
constexpr int YZ = Y * Z;            // 8192
constexpr int GEND = 24 * NV;

__device__ __forceinline__ int iclamp(int v, int lo, int hi) {
    return min(max(v, lo), hi);
}

template <int DIR>
__device__ __forceinline__ void do_group(int f0, const float* __restrict__ g,
                                         const float* __restrict__ src,
                                         float* __restrict__ dst) {
    constexpr int d1[8] = {1, 1, 1, 0, 0, -1, -1, -1};
    constexpr int d2[8] = {1, 0, -1, 1, -1, 1, 0, -1};
    const int z = f0 & 31, y = (f0 >> 5) & 255, x = f0 >> 13;
    const int gb0 = DIR * 8 * NV;

    float asx = 0, asy = 0, asz = 0, asw = 0;
    float dx = 0, dy = 0, dz = 0, dw = 0;
    float4 rc;

    if (DIR == 0) {
        rc = *(const float4*)(src + f0);
#pragma unroll
        for (int k = 0; k < 8; ++k) {
            const int a = x + d1[k], b = y + d2[k];
            const bool valid = ((unsigned)a < 256u) & ((unsigned)b < 256u);
            const int ofs = f0 + d1[k] * YZ + d2[k] * Z;
            const float4 rv = *(const float4*)(src + iclamp(ofs, 0, NV - 4));
            float4 gv = *(const float4*)(g + iclamp(gb0 + k * NV + ofs, 0, GEND - 4));
            if (!valid) { gv.x = 0.f; gv.y = 0.f; gv.z = 0.f; gv.w = 0.f; }
            asx += fabsf(gv.x); asy += fabsf(gv.y);
            asz += fabsf(gv.z); asw += fabsf(gv.w);
            dx = fmaf(gv.x, rv.x - rc.x, dx); dy = fmaf(gv.y, rv.y - rc.y, dy);
            dz = fmaf(gv.z, rv.z - rc.z, dz); dw = fmaf(gv.w, rv.w - rc.w, dw);
        }
    } else {
        const int s1 = (DIR == 1) ? YZ : Z;   // d1 stride: x or y
        const int c1 = (DIR == 1) ? x : y;
        float4 rv[3]; float rl[3], rr[3];
#pragma unroll
        for (int j = 0; j < 3; ++j) {
            const int ro = f0 + (1 - j) * s1;
            rv[j] = *(const float4*)(src + iclamp(ro, 0, NV - 4));
            rl[j] = src[iclamp(ro - 1, 0, NV - 1)];
            rr[j] = src[iclamp(ro + 4, 0, NV - 1)];
        }
        rc = rv[1];
        const bool zlo = (z > 0), zhi = (z < Z - 4);
#pragma unroll
        for (int k = 0; k < 8; ++k) {
            const int j = 1 - d1[k];
            const bool vrow = (unsigned)(c1 + d1[k]) < 256u;
            const int gb = gb0 + k * NV + f0 + d1[k] * s1;
            float4 gv = *(const float4*)(g + iclamp(gb, 0, GEND - 4));
            if (!vrow) { gv.x = 0.f; gv.y = 0.f; gv.z = 0.f; gv.w = 0.f; }
            float4 gk, rk;
            if (d2[k] == 1) {
                float ge = g[iclamp(gb + 4, 0, GEND - 1)];
                ge = (vrow && zhi) ? ge : 0.f;
                gk = make_float4(gv.y, gv.z, gv.w, ge);
                rk = make_float4(rv[j].y, rv[j].z, rv[j].w, rr[j]);
            } else if (d2[k] == -1) {
                float ge = g[iclamp(gb - 1, 0, GEND - 1)];
                ge = (vrow && zlo) ? ge : 0.f;
                gk = make_float4(ge, gv.x, gv.y, gv.z);
                rk = make_float4(rl[j], rv[j].x, rv[j].y, rv[j].z);
            } else {
                gk = gv; rk = rv[j];
            }
            asx += fabsf(gk.x); asy += fabsf(gk.y);
            asz += fabsf(gk.z); asw += fabsf(gk.w);
            dx = fmaf(gk.x, rk.x - rc.x, dx); dy = fmaf(gk.y, rk.y - rc.y, dy);
            dz = fmaf(gk.z, rk.z - rc.z, dz); dw = fmaf(gk.w, rk.w - rc.w, dw);
        }
    }

    float4 o;
    o.x = rc.x + dx * __builtin_amdgcn_rcpf(asx);
    o.y = rc.y + dy * __builtin_amdgcn_rcpf(asy);
    o.z = rc.z + dz * __builtin_amdgcn_rcpf(asz);
    o.w = rc.w + dw * __builtin_amdgcn_rcpf(asw);
    *(float4*)(dst + f0) = o;
}

// ---- fused cooperative kernel: 256 blocks x 256 threads, 8 groups/thread ----
constexpr int NTH = 256 * 256;            // 65536 threads
constexpr int GRP = NV / 4 / NTH;         // 8 float4-groups per thread

__global__ __launch_bounds__(256, 1) void prop_all(const float* __restrict__ g,
                                                   const float* __restrict__ blur,
                                                   float* __restrict__ bufA,
                                                   float* __restrict__ bufB,
                                                   float* __restrict__ out) {
    cg::grid_group grid = cg::this_grid();
    const int u = blockIdx.x * 256 + threadIdx.x;

    for (int step = 0; step < 9; ++step) {
        const float* src = (step == 0) ? blur : ((step & 1) ? bufA : bufB);
        float* dst = (step == 8) ? out : ((step & 1) ? bufB : bufA);
        const int dir = step % 3;

        if (dir == 0) {
#pragma unroll 2
            for (int j = 0; j < GRP; ++j) do_group<0>((u + j * NTH) << 2, g, src, dst);
        } else if (dir == 1) {
#pragma unroll 2
            for (int j = 0; j < GRP; ++j) do_group<1>((u + j * NTH) << 2, g, src, dst);
        } else {
#pragma unroll 2
            for (int j = 0; j < GRP; ++j) do_group<2>((u + j * NTH) << 2, g, src, dst);
        }
        if (step < 8) {
            __threadfence();   // device-scope release (cross-XCD visibility)
            grid.sync();
        }
    }
}

// ---- fallback: one dispatch per step (known-good R1-style path) ----
template <int DIR>
__global__ __launch_bounds__(256) void prop_step(const float* __restrict__ g,
                                                 const float* __restrict__ rin,
                                                 float* __restrict__ rout) {
    const int t = blockIdx.x * 256 + threadIdx.x;
    do_group<DIR>(t << 2, g, rin, rout);
}

extern "C" void kernel_launch(void* const* d_in, const int* in_sizes, int n_in,
                              void* d_out, int out_size, void* d_ws, size_t ws_size,
                              hipStream_t stream) {
    const float* g    = (const float*)d_in[0];
    const float* blur = (const float*)d_in[1];
    float* out  = (float*)d_out;
    float* bufA = (float*)d_ws;
    float* bufB = bufA + NV;

    void* args[] = {(void*)&g, (void*)&blur, (void*)&bufA, (void*)&bufB, (void*)&out};
    hipError_t err = hipLaunchCooperativeKernel((void*)prop_all, dim3(256), dim3(256),
                                                args, 0, stream);
    if (err != hipSuccess) {
        (void)hipGetLastError();  // clear sticky error, fall back to 9 dispatches
        const dim3 grid(NV / 1024), block(256);
        const float* src = blur;
        for (int step = 0; step < 9; ++step) {
            float* dst = (step == 8) ? out : ((step & 1) ? bufB : bufA);
            // match fused ping-pong: s0: blur->A, s1: A->B, s2: B->A, ...
            if (step < 8) dst = (step & 1) ? bufB : bufA;
            switch (step % 3) {
                case 0: prop_step<0><<<grid, block, 0, stream>>>(g, src, dst); break;
                case 1: prop_step<1><<<grid, block, 0, stream>>>(g, src, dst); break;
                case 2: prop_step<2><<<grid, block, 0, stream>>>(g, src, dst); break;
            }
            src = dst;
        }
    }
}